// Round 11
// baseline (101682.721 us; speedup 1.0000x reference)
//
#include <hip/hip_runtime.h>
#include <hip/hip_cooperative_groups.h>

namespace cg = cooperative_groups;

#define NPTS 8192
#define N2 (NPTS * 2)
#define TPB 1024
#define NBLK 256           // 1 block/CU, cooperative co-resident
#define IPB 32             // i-rows owned per block
#define IB 8               // i-rows per thread
#define NJS 256            // j-slices
#define NCHK 8             // staging chunks
#define JCH (NPTS / NCHK)  // 1024 j per chunk
#define T_ITERS 1152
#define NUG 1.0e-4
#define LAM 1.0e-5

typedef float v2f __attribute__((ext_vector_type(2)));

#if __has_builtin(__builtin_amdgcn_exp2f)
#define EXP2F(x) __builtin_amdgcn_exp2f(x)
#else
#define EXP2F(x) __expf(0.6931471805599453f * (x))
#endif

// ---------------- setup ----------------
// u = x / sqrt(2 ln2)  =>  K_ij = 2^(u_i.w_j - n_i - n_j), w = 2u (SoA)
extern "C" __global__ void __launch_bounds__(256)
k_setup(const float* __restrict__ Xmu, const float* __restrict__ Yeta,
        const float* __restrict__ Ymu, const float* __restrict__ Z,
        float4* __restrict__ U4, float* __restrict__ WX, float* __restrict__ WY,
        float* __restrict__ WZ, float* __restrict__ WW, float* __restrict__ NS,
        float4* __restrict__ M4, float4* __restrict__ Y4,
        float4* __restrict__ SA1, float2* __restrict__ SB1,
        double* __restrict__ rrsetup)
{
  const float c2 = 0.84932180028802f;        // 1/sqrt(2 ln 2)
  int tid = threadIdx.x;
  int idx = blockIdx.x * 256 + tid;          // 0..16383 (64 blocks)
  int i = idx >> 1;
  float z = Z[idx];
  if ((idx & 1) == 0) {
    float a0 = Xmu[2 * i], a1 = Xmu[2 * i + 1];
    float e0 = Yeta[2 * i], e1 = Yeta[2 * i + 1];
    float m0 = Ymu[2 * i], m1 = Ymu[2 * i + 1];
    float z0 = Z[2 * i], z1 = Z[2 * i + 1];
    float u0 = c2 * a0, u1 = c2 * a1, u2 = c2 * e0, u3 = c2 * e1;
    float n = fmaf(u3, u3, fmaf(u2, u2, fmaf(u1, u1, u0 * u0)));
    U4[i] = make_float4(u0, u1, u2, u3);
    WX[i] = 2.f * u0; WY[i] = 2.f * u1; WZ[i] = 2.f * u2; WW[i] = 2.f * u3;
    NS[i] = n;
    M4[i] = make_float4(a0, a1, e0 + z0, e1 + z1);
    Y4[i] = make_float4(a0, a1, m0, m1);
    SA1[i] = make_float4(z0, z1, 0.f, 0.f);  // (r0,r1,p0,p1) at t=0
    SB1[i] = make_float2(0.f, 0.f);          // (q0,q1) at t=0
  }
  __shared__ double sd[256];
  sd[tid] = (double)z * (double)z;
  __syncthreads();
  for (int st = 128; st >= 2; st >>= 1) {
    if (tid < st) sd[tid] += sd[tid + st];
    __syncthreads();
  }
  if (tid < 2) rrsetup[blockIdx.x * 2 + tid] = sd[tid];   // 128 entries
}

// ---------------- MMD: three fused Gram sums ----------------
#define MTPB 256
#define MCH 1024
extern "C" __global__ void __launch_bounds__(MTPB)
k_mmd(const float4* __restrict__ M4, const float4* __restrict__ Y4,
      double* __restrict__ mmdpart)
{
  __shared__ float4 sM[MCH];
  __shared__ float4 sY[MCH];
  __shared__ double sred[MTPB];
  int tid = threadIdx.x;
  int blk = blockIdx.x;            // 256 = 32 itiles x 8 chunks
  int itile = blk >> 3;
  int ch = blk & 7;
  int j0 = ch * MCH;
  for (int u = tid; u < MCH; u += MTPB) {
    sM[u] = M4[j0 + u];
    sY[u] = Y4[j0 + u];
  }
  __syncthreads();
  int i = itile * MTPB + tid;
  float4 mi = M4[i];
  float4 yi = Y4[i];
  double szz = 0.0, szy = 0.0, syy = 0.0;
  for (int jj = 0; jj < MCH; ++jj) {
    float4 mj = sM[jj];
    float4 yj = sY[jj];
    float d0 = mi.x - mj.x, d1 = mi.y - mj.y;
    float a = fmaf(d1, d1, d0 * d0);
    float u0 = mi.z - mj.z, u1 = mi.w - mj.w;
    float v0 = mi.z - yj.z, v1 = mi.w - yj.w;
    float w0 = yi.z - yj.z, w1 = yi.w - yj.w;
    float dzz = fmaf(u0, u0, fmaf(u1, u1, a));
    float dzy = fmaf(v0, v0, fmaf(v1, v1, a));
    float dyy = fmaf(w0, w0, fmaf(w1, w1, a));
    szz += (double)__expf(-0.5f * dzz);
    szy += (double)__expf(-0.5f * dzy);
    syy += (double)__expf(-0.5f * dyy);
  }
  double v[3] = {szz, szy, syy};
  for (int k = 0; k < 3; ++k) {
    sred[tid] = v[k];
    __syncthreads();
    for (int st = MTPB >> 1; st >= 1; st >>= 1) {
      if (tid < st) sred[tid] += sred[tid + st];
      __syncthreads();
    }
    if (tid == 0) mmdpart[blk * 3 + k] = sred[0];
    __syncthreads();
  }
}

// ---------------- persistent CG: all iterations, 1 grid.sync each ----------------
// Body = R10's k_it (chunk-pipelined staging, packed v2f math); owner f64 CG
// state lives in registers (tid<64 owns (row = blk*32 + tid/2, col = tid&1)).
extern "C" __global__ void __launch_bounds__(TPB, 4)
k_cg_persist(const float4* __restrict__ U4,
             const float* __restrict__ WX, const float* __restrict__ WY,
             const float* __restrict__ WZ, const float* __restrict__ WW,
             const float* __restrict__ NS, const float* __restrict__ Z,
             float4* __restrict__ SA0, float4* __restrict__ SA1,
             float2* __restrict__ SB0, float2* __restrict__ SB1,
             double* __restrict__ xout, double* __restrict__ pout,
             double* __restrict__ part0, double* __restrict__ part1,
             double* __restrict__ rho0, double* __restrict__ rho1,
             const double* __restrict__ rrsetup)
{
  cg::grid_group grid = cg::this_grid();
  __shared__ float sp0[NPTS];                // pn col0 (SoA)       32 KB
  __shared__ float sp1[NPTS];                // pn col1             32 KB
  __shared__ double s1[TPB], s2[TPB], s3[TPB];                  // 24 KB
  __shared__ float qred[16][IB][2];          // per-wave partials   1 KB
  __shared__ double sc[4];                   // a0,a1,b0,b1

  int tid = threadIdx.x;
  int blk = blockIdx.x;
  int ig = tid >> 8;                         // 0..3
  int js = tid & (NJS - 1);                  // 0..255
  int i0 = blk * IPB + ig * IB;

  float4 ui[IB];
  float ni[IB];
#pragma unroll
  for (int k = 0; k < IB; ++k) { ui[k] = U4[i0 + k]; ni[k] = NS[i0 + k]; }

  // owner f64 CG state in registers
  int oidx = blk * (2 * IPB) + tid;          // valid for tid<64
  double r_o = 0.0, p_o = 0.0, q_o = 0.0, x_o = 0.0;
  if (tid < 2 * IPB) r_o = (double)Z[oidx];

  for (int t = 0; t < T_ITERS; ++t) {
    const float4* SAr = (t & 1) ? SA0 : SA1;
    const float2* SBr = (t & 1) ? SB0 : SB1;
    float4* SAw = (t & 1) ? SA1 : SA0;
    float2* SBw = (t & 1) ? SB1 : SB0;
    const double* partr = (t & 1) ? part0 : part1;
    double* partw = (t & 1) ? part1 : part0;
    const double* rhor = (t & 1) ? rho0 : rho1;
    double* rhow = (t & 1) ? rho1 : rho0;

    // ---- issue chunk-0 staging loads before the scalar phase ----
    float4 sa_r = SAr[tid];                  // chunk 0: j = tid
    float2 sb_r = SBr[tid];

    // ---- scalar phase (redundant per block, deterministic) ----
    if (t == 0) {
      s1[tid] = (tid < 128) ? rrsetup[tid] : 0.0;
      __syncthreads();
      for (int st = 64; st >= 2; st >>= 1) {
        if (tid < st) s1[tid] += s1[tid + st];
        __syncthreads();
      }
      if (tid < 2) { rhow[tid] = s1[tid]; sc[tid] = 0.0; sc[2 + tid] = 0.0; }
      __syncthreads();
    } else {
      s1[tid] = (tid < 512) ? partr[tid] : 0.0;
      s2[tid] = (tid < 512) ? partr[512 + tid] : 0.0;
      s3[tid] = (tid < 512) ? partr[1024 + tid] : 0.0;
      __syncthreads();
      for (int st = 512; st >= 2; st >>= 1) {
        if (tid < st) {
          s1[tid] += s1[tid + st];
          s2[tid] += s2[tid + st];
          s3[tid] += s3[tid + st];
        }
        __syncthreads();
      }
      if (tid < 2) {
        double rho_o = rhor[tid];
        double al = rho_o / s1[tid];
        double rho_n = fma(al, fma(al, s3[tid], -2.0 * s2[tid]), rho_o);
        rhow[tid] = rho_n;                   // identical dup-write per block
        sc[tid] = al;
        sc[2 + tid] = rho_n / rho_o;
      }
      __syncthreads();
    }
    double da0 = sc[0], da1 = sc[1], db0 = sc[2], db1 = sc[3];
    float a0 = (float)da0, a1 = (float)da1, b0 = (float)db0, b1 = (float)db1;

    v2f qa0[IB], qa1[IB];
#pragma unroll
    for (int k = 0; k < IB; ++k) { qa0[k] = (v2f)(0.f); qa1[k] = (v2f)(0.f); }

    // ---- chunk-pipelined: write chunk c, sync, compute c while loading c+1 ----
    sp0[tid] = fmaf(b0, sa_r.z, fmaf(-a0, sb_r.x, sa_r.x));
    sp1[tid] = fmaf(b1, sa_r.w, fmaf(-a1, sb_r.y, sa_r.y));
    __syncthreads();
    for (int c = 0; c < NCHK; ++c) {
      if (c + 1 < NCHK) {                    // prefetch next chunk into regs
        int j = (c + 1) * JCH + tid;
        sa_r = SAr[j];
        sb_r = SBr[j];
      }
#pragma unroll
      for (int jj = 0; jj < 2; ++jj) {
        int jp = c * (JCH / 2) + jj * NJS + js;        // pair index
        v2f wx = ((const v2f*)WX)[jp];
        v2f wy = ((const v2f*)WY)[jp];
        v2f wz = ((const v2f*)WZ)[jp];
        v2f ww = ((const v2f*)WW)[jp];
        v2f nj = ((const v2f*)NS)[jp];
        v2f pn0 = ((const v2f*)sp0)[jp];
        v2f pn1 = ((const v2f*)sp1)[jp];
#pragma unroll
        for (int k = 0; k < IB; ++k) {
          v2f tt = -nj - ni[k];
          tt += ui[k].x * wx;                // contracts to v_pk_fma_f32
          tt += ui[k].y * wy;
          tt += ui[k].z * wz;
          tt += ui[k].w * ww;
          v2f e;
          e.x = EXP2F(tt.x);
          e.y = EXP2F(tt.y);
          qa0[k] += e * pn0;
          qa1[k] += e * pn1;
        }
      }
      if (c + 1 < NCHK) {                    // disjoint sp region: no WAR
        int j = (c + 1) * JCH + tid;
        sp0[j] = fmaf(b0, sa_r.z, fmaf(-a0, sb_r.x, sa_r.x));
        sp1[j] = fmaf(b1, sa_r.w, fmaf(-a1, sb_r.y, sa_r.y));
        __syncthreads();
      }
    }

    // ---- reduce: fold pair, wave shuffle, cross-wave via LDS ----
    float q0s[IB], q1s[IB];
#pragma unroll
    for (int k = 0; k < IB; ++k) {
      q0s[k] = qa0[k].x + qa0[k].y;
      q1s[k] = qa1[k].x + qa1[k].y;
#pragma unroll
      for (int d = 32; d >= 1; d >>= 1) {
        q0s[k] += __shfl_down(q0s[k], (unsigned)d, 64);
        q1s[k] += __shfl_down(q1s[k], (unsigned)d, 64);
      }
    }
    {
      int lane = tid & 63, wv = tid >> 6;    // 16 waves; ig = wv>>2
      if (lane == 0) {
#pragma unroll
        for (int k = 0; k < IB; ++k) {
          qred[wv][k][0] = q0s[k];
          qred[wv][k][1] = q1s[k];
        }
      }
    }
    __syncthreads();

    // ---- epilogue: owner rows (tid<64), f64 recurrence in registers ----
    double pqv = 0.0, rqv = 0.0, qqv = 0.0;
    if (tid < 2 * IPB) {
      int io = tid >> 1, col = tid & 1;
      int wb = (io >> 3) * 4, k = io & 7;
      double qg = (double)qred[wb][k][col] + (double)qred[wb + 1][k][col]
                + (double)qred[wb + 2][k][col] + (double)qred[wb + 3][k][col];
      double al = col ? da1 : da0;
      double be = col ? db1 : db0;
      double rn = fma(-al, q_o, r_o);        // r_t
      double pn = fma(be, p_o, rn);          // p_t
      double xn = fma(al, p_o, x_o);         // x_t
      double qn = fma((double)NUG, pn, qg);  // q_t
      r_o = rn; p_o = pn; q_o = qn; x_o = xn;
      int i = blk * IPB + io;
      float* SAf = (float*)SAw;
      float* SBf = (float*)SBw;
      SAf[i * 4 + col] = (float)rn;
      SAf[i * 4 + 2 + col] = (float)pn;
      SBf[i * 2 + col] = (float)qn;
      pqv = pn * qn;
      rqv = rn * qn;
      qqv = qn * qn;
    }
    s1[tid] = pqv; s2[tid] = rqv; s3[tid] = qqv;
    __syncthreads();
    for (int st = IPB; st >= 2; st >>= 1) {
      if (tid < st) {
        s1[tid] += s1[tid + st];
        s2[tid] += s2[tid + st];
        s3[tid] += s3[tid + st];
      }
      __syncthreads();
    }
    if (tid < 2) {
      partw[blk * 2 + tid] = s1[tid];
      partw[512 + blk * 2 + tid] = s2[tid];
      partw[1024 + blk * 2 + tid] = s3[tid];
    }
    grid.sync();
  }
  if (tid < 2 * IPB) {
    xout[oidx] = x_o;
    pout[oidx] = p_o;
  }
}

// ---------------- final: last x half-step + combine ----------------
extern "C" __global__ void __launch_bounds__(256)
k_final(const float* __restrict__ Z, const double* __restrict__ x64,
        const double* __restrict__ p64, const double* __restrict__ part_last,
        const double* __restrict__ rho_last, const double* __restrict__ mmdpart,
        float* __restrict__ out)
{
  __shared__ double s1[256];
  __shared__ double sc2[2];
  int tid = threadIdx.x;
  s1[tid] = part_last[tid] + part_last[tid + 256];
  __syncthreads();
  for (int st = 128; st >= 2; st >>= 1) {
    if (tid < st) s1[tid] += s1[tid + st];
    __syncthreads();
  }
  if (tid < 2) sc2[tid] = rho_last[tid] / s1[tid];
  __syncthreads();
  double al = sc2[tid & 1];
  double zx = 0.0;
  for (int idx = tid; idx < N2; idx += 256)   // stride even: parity fixed
    zx += (double)Z[idx] * fma(al, p64[idx], x64[idx]);
  double acc[4];
  acc[0] = zx;
  acc[1] = mmdpart[tid * 3 + 0];
  acc[2] = mmdpart[tid * 3 + 1];
  acc[3] = mmdpart[tid * 3 + 2];
  double tot[4];
  for (int k = 0; k < 4; ++k) {
    s1[tid] = acc[k];
    __syncthreads();
    for (int st = 128; st >= 1; st >>= 1) {
      if (tid < st) s1[tid] += s1[tid + st];
      __syncthreads();
    }
    tot[k] = s1[0];
    __syncthreads();
  }
  if (tid == 0) {
    double nn = (double)NPTS * (double)NPTS;
    double mmd = (tot[1] - 2.0 * tot[2] + tot[3]) / nn;
    out[0] = (float)(mmd + LAM * tot[0]);
  }
}

extern "C" void kernel_launch(void* const* d_in, const int* in_sizes, int n_in,
                              void* d_out, int out_size, void* d_ws, size_t ws_size,
                              hipStream_t stream)
{
  (void)in_sizes; (void)n_in; (void)out_size; (void)ws_size;
  const float* Xmu  = (const float*)d_in[0];
  const float* Yeta = (const float*)d_in[1];
  const float* Ymu  = (const float*)d_in[2];
  const float* Z    = (const float*)d_in[3];
  float* out = (float*)d_out;

  char* w = (char*)d_ws;
  float4* U4      = (float4*)(w);                      // 128K
  float*  WX      = (float*)(w + (128 << 10));         // 32K
  float*  WY      = (float*)(w + (160 << 10));         // 32K
  float*  WZ      = (float*)(w + (192 << 10));         // 32K
  float*  WW      = (float*)(w + (224 << 10));         // 32K
  float*  NS      = (float*)(w + (256 << 10));         // 32K
  float4* M4      = (float4*)(w + (288 << 10));        // 128K
  float4* Y4      = (float4*)(w + (416 << 10));        // 128K
  float4* SA0     = (float4*)(w + (544 << 10));        // 128K
  float4* SA1     = (float4*)(w + (672 << 10));        // 128K
  float2* SB0     = (float2*)(w + (800 << 10));        // 64K
  float2* SB1     = (float2*)(w + (864 << 10));        // 64K
  double* xout    = (double*)(w + (928 << 10));        // 128K
  double* pout    = (double*)(w + (1056 << 10));       // 128K
  double* part0   = (double*)(w + (1184 << 10));       // 12K
  double* part1   = (double*)(w + (1200 << 10));       // 12K
  double* rho0    = (double*)(w + (1216 << 10));
  double* rho1    = (double*)(w + (1216 << 10) + 64);
  double* rrsetup = (double*)(w + (1217 << 10));       // 1K
  double* mmdpart = (double*)(w + (1218 << 10));       // 6K

  hipLaunchKernelGGL(k_setup, dim3(64), dim3(256), 0, stream,
                     Xmu, Yeta, Ymu, Z, U4, WX, WY, WZ, WW, NS, M4, Y4,
                     SA1, SB1, rrsetup);
  hipLaunchKernelGGL(k_mmd, dim3(256), dim3(MTPB), 0, stream, M4, Y4, mmdpart);

  {
    const float4* a0 = U4;
    const float* a1 = WX; const float* a2 = WY;
    const float* a3 = WZ; const float* a4 = WW;
    const float* a5 = NS; const float* a6 = Z;
    float4* a7 = SA0; float4* a8 = SA1;
    float2* a9 = SB0; float2* a10 = SB1;
    double* a11 = xout; double* a12 = pout;
    double* a13 = part0; double* a14 = part1;
    double* a15 = rho0; double* a16 = rho1;
    const double* a17 = rrsetup;
    void* args[] = {&a0, &a1, &a2, &a3, &a4, &a5, &a6, &a7, &a8, &a9,
                    &a10, &a11, &a12, &a13, &a14, &a15, &a16, &a17};
    hipLaunchCooperativeKernel((void*)k_cg_persist, dim3(NBLK), dim3(TPB),
                               args, 0, stream);
  }

  int last = (T_ITERS - 1) & 1;   // = 1
  hipLaunchKernelGGL(k_final, dim3(1), dim3(256), 0, stream,
                     Z, xout, pout, last ? part1 : part0,
                     last ? rho1 : rho0, mmdpart, out);
}